// Round 1
// baseline (647.146 us; speedup 1.0000x reference)
//
#include <hip/hip_runtime.h>

#define DEVINL static __device__ __forceinline__

constexpr int NUSER = 100000;
constexpr int D     = 128;
constexpr int KDIM  = 128;
constexpr int SDIM  = 128;
constexpr int RIN   = D + KDIM + 1;          // 257
constexpr int METAN = 2*SDIM + 2*D + KDIM;   // 640
constexpr int NT    = 256;                   // threads per block
constexpr int GMAIN = 256;                   // 1 block per CU -> guaranteed co-resident

struct Params {
  const float *emb_in, *stat, *kg;
  const float *Wihu, *bihu, *Whhu, *bhhu;
  const float *Wihl, *bihl, *Whhl, *bhhl;
  const float *wproj, *bproj, *lng, *lnb, *Wpred, *bpred;
  const float *deltau, *deltal;
  const int *idxu, *idxl, *idxp, *idxk;
  float *emb;        // d_out embedding area (N*D floats)
  float *loss_slot;  // d_out + N*D
  float *loss_ev;    // ws: E floats
  int *cnt_u;        // ws: NUSER ints  (completed touches of user row; all touches are writes)
  int *cnt_w;        // ws: NLOC ints   (completed writes of loca row)
  int *cnt_t;        // ws: NLOC ints   (completed touch-slots of loca row: il-writes + ip-reads)
  int E, N, NLOC;
};

DEVINL float loadx(const float* p) {
  return __hip_atomic_load((const float*)p, __ATOMIC_RELAXED, __HIP_MEMORY_SCOPE_AGENT);
}
DEVINL void storex(float* p, float v) {
  __hip_atomic_store(p, v, __ATOMIC_RELAXED, __HIP_MEMORY_SCOPE_AGENT);
}

DEVINL float warp_allreduce_sum(float v) {
  #pragma unroll
  for (int o = 32; o; o >>= 1) v += __shfl_xor(v, o, 64);
  return v;
}

DEVINL float block_sum(float v, float* s_red) {
  #pragma unroll
  for (int o = 32; o; o >>= 1) v += __shfl_xor(v, o, 64);
  if ((threadIdx.x & 63) == 0) s_red[threadIdx.x >> 6] = v;
  __syncthreads();
  v = s_red[0] + s_red[1] + s_red[2] + s_red[3];
  __syncthreads();
  return v;
}

__global__ void k_init(Params p) {
  size_t tid = (size_t)blockIdx.x * blockDim.x + threadIdx.x;
  size_t stride = (size_t)gridDim.x * blockDim.x;
  size_t n4 = (size_t)p.N * D / 4;
  const float4* src = (const float4*)p.emb_in;
  float4* dst = (float4*)p.emb;
  for (size_t i = tid; i < n4; i += stride) dst[i] = src[i];
  for (size_t i = tid; i < (size_t)NUSER; i += stride) p.cnt_u[i] = 0;
  for (size_t i = tid; i < (size_t)p.NLOC; i += stride) { p.cnt_w[i] = 0; p.cnt_t[i] = 0; }
}

__global__ __launch_bounds__(NT) void k_main(Params p) {
  __shared__ float s_u[D], s_l[D], s_p[D], s_kg[KDIM], s_sil[SDIM];
  __shared__ float s_meta[METAN];
  __shared__ float s_nu[D], s_nl[D];
  __shared__ float s_red[4];
  __shared__ unsigned long long s_redu[4];

  const int tid  = threadIdx.x;
  const int w    = tid >> 6;
  const int lane = tid & 63;

  for (int t = blockIdx.x; t < p.E; t += gridDim.x) {
    const int iu = p.idxu[t];
    const int il = p.idxl[t];
    const int ip = p.idxp[t];
    const int ik = p.idxk[t];
    const int ilr = il + NUSER;
    const int ipr = ip + NUSER;
    const float du = p.deltau[t], dl = p.deltal[t];

    // ---- dependency wait-counts (per-slot counting over earlier events) ----
    int a = 0, b = 0, c = 0;
    for (int s = tid; s < t; s += NT) {
      int ius = p.idxu[s], ils = p.idxl[s], ips = p.idxp[s];
      a += (ius == iu);
      b += (ils == il) + (ips == il);   // earlier writes + reads of our write-row
      c += (ils == ip);                 // earlier writes of our read-row
    }
    unsigned long long pk = (unsigned long long)a
                          | ((unsigned long long)b << 16)
                          | ((unsigned long long)c << 32);
    #pragma unroll
    for (int o = 32; o; o >>= 1) pk += __shfl_xor(pk, o, 64);
    if (lane == 0) s_redu[w] = pk;
    __syncthreads();
    pk = s_redu[0] + s_redu[1] + s_redu[2] + s_redu[3];
    __syncthreads();
    const int A = (int)(pk & 0xffff);
    const int B = (int)((pk >> 16) & 0xffff);
    const int C = (int)((pk >> 32) & 0xffff);

    // ---- spin until all predecessors complete ----
    if (tid == 0) {
      int guard = 0;
      while (true) {
        int x = __hip_atomic_load(&p.cnt_u[iu], __ATOMIC_RELAXED, __HIP_MEMORY_SCOPE_AGENT);
        int y = __hip_atomic_load(&p.cnt_t[il], __ATOMIC_RELAXED, __HIP_MEMORY_SCOPE_AGENT);
        int z = __hip_atomic_load(&p.cnt_w[ip], __ATOMIC_RELAXED, __HIP_MEMORY_SCOPE_AGENT);
        if (x >= A && y >= B && z >= C) break;
        if (++guard > (1 << 22)) break;   // safety valve: terminate instead of hang
        __builtin_amdgcn_s_sleep(1);
      }
    }
    __syncthreads();

    // ---- load rows (emb rows via LLC-coherent loads; constants via cached loads) ----
    if (tid < D) {
      int i = tid;
      s_u[i]  = loadx(p.emb + (size_t)iu  * D + i);
      s_l[i]  = loadx(p.emb + (size_t)ilr * D + i);
      s_p[i]  = loadx(p.emb + (size_t)ipr * D + i);
      s_kg[i] = p.kg[(size_t)ik * KDIM + i];
      s_sil[i]        = p.stat[(size_t)ilr * SDIM + i];
      s_meta[384 + i] = p.stat[(size_t)ipr * SDIM + i];
      s_meta[512 + i] = p.stat[(size_t)iu  * SDIM + i];
    }
    __syncthreads();

    // ---- LayerNorm over [p ; kg] and projection ----
    float xln = (tid < D) ? s_p[tid] : s_kg[tid - D];
    float mu  = block_sum(xln, s_red) * (1.f / 256.f);
    float dx  = xln - mu;
    float var = block_sum(dx * dx, s_red) * (1.f / 256.f);
    float rstd = rsqrtf(var + 1e-5f);
    s_meta[D + tid] = dx * rstd * p.lng[tid] + p.lnb[tid];
    if (tid < D) s_meta[tid] = s_u[tid] * (1.f + p.wproj[tid] * du + p.bproj[tid]);
    __syncthreads();

    // ---- pred = W_pred @ meta + b_pred ; loss_pred ----
    float predj = 0.f;
    for (int jj = 0; jj < 64; ++jj) {
      const float* row = p.Wpred + (size_t)(w * 64 + jj) * METAN;
      float acc = 0.f;
      #pragma unroll
      for (int cc = 0; cc < 10; ++cc) acc += row[cc * 64 + lane] * s_meta[cc * 64 + lane];
      acc = warp_allreduce_sum(acc);
      if (lane == jj) predj = acc;
    }
    {
      int j = w * 64 + lane;
      predj += p.bpred[j];
      float tg = (j < D) ? s_l[j] : s_sil[j - D];
      float e = predj - tg;
      float lossp = block_sum(e * e, s_red) * (1.f / 256.f);

      // ---- RNN cells (u and l), wave-per-output dot products ----
      for (int ii = 0; ii < 32; ++ii) {
        int i = w * 32 + ii;
        { // user cell: x_u = [l ; kg ; du], hidden u
          const float* ri = p.Wihu + (size_t)i * RIN;
          const float* rh = p.Whhu + (size_t)i * D;
          float acc = 0.f;
          #pragma unroll
          for (int cc = 0; cc < 4; ++cc) {
            int k = cc * 64 + lane;
            float xv = (k < D) ? s_l[k] : s_kg[k - D];
            acc += ri[k] * xv;
          }
          if (lane == 0) acc += ri[256] * du;
          #pragma unroll
          for (int cc = 0; cc < 2; ++cc) acc += rh[cc * 64 + lane] * s_u[cc * 64 + lane];
          acc = warp_allreduce_sum(acc);
          if (lane == 0) s_nu[i] = tanhf(acc + p.bihu[i] + p.bhhu[i]);
        }
        { // location cell: x_l = [u ; kg ; dl], hidden l
          const float* ri = p.Wihl + (size_t)i * RIN;
          const float* rh = p.Whhl + (size_t)i * D;
          float acc = 0.f;
          #pragma unroll
          for (int cc = 0; cc < 4; ++cc) {
            int k = cc * 64 + lane;
            float xv = (k < D) ? s_u[k] : s_kg[k - D];
            acc += ri[k] * xv;
          }
          if (lane == 0) acc += ri[256] * dl;
          #pragma unroll
          for (int cc = 0; cc < 2; ++cc) acc += rh[cc * 64 + lane] * s_l[cc * 64 + lane];
          acc = warp_allreduce_sum(acc);
          if (lane == 0) s_nl[i] = tanhf(acc + p.bihl[i] + p.bhhl[i]);
        }
      }
      __syncthreads();

      // ---- L2-normalize, embedding losses, write back ----
      float vu  = (tid < D) ? s_nu[tid] : 0.f;
      float ssu = block_sum(vu * vu, s_red);
      float inv_u = 1.f / fmaxf(sqrtf(ssu), 1e-12f);
      float eu  = (tid < D) ? (vu * inv_u - s_u[tid]) : 0.f;
      float lossu = block_sum(eu * eu, s_red) * (1.f / 128.f);

      float vl  = (tid < D) ? s_nl[tid] : 0.f;
      float ssl = block_sum(vl * vl, s_red);
      float inv_l = 1.f / fmaxf(sqrtf(ssl), 1e-12f);
      float el  = (tid < D) ? (vl * inv_l - s_l[tid]) : 0.f;
      float lossl = block_sum(el * el, s_red) * (1.f / 128.f);

      if (tid == 0) p.loss_ev[t] = lossp + lossu + lossl;

      if (tid < D) {
        storex(p.emb + (size_t)iu * D + tid, vu * inv_u);
      } else {
        int i2 = tid - D;
        storex(p.emb + (size_t)ilr * D + i2, s_nl[i2] * inv_l);
      }
    }
    __syncthreads();   // drain all stores (implies vmcnt(0))

    if (tid == 0) {
      __threadfence();                 // release: row data at LLC before counters bump
      atomicAdd(&p.cnt_u[iu], 1);      // write of user row
      atomicAdd(&p.cnt_t[il], 1);      // write-touch of loca row il
      atomicAdd(&p.cnt_w[il], 1);
      atomicAdd(&p.cnt_t[ip], 1);      // read-touch of loca row ip
    }
  }
}

__global__ void k_fin(Params p) {
  __shared__ float s_red[4];
  float v = 0.f;
  for (int i = threadIdx.x; i < p.E; i += NT) v += p.loss_ev[i];
  v = block_sum(v, s_red);
  if (threadIdx.x == 0) p.loss_slot[0] = v;
}

extern "C" void kernel_launch(void* const* d_in, const int* in_sizes, int n_in,
                              void* d_out, int out_size, void* d_ws, size_t ws_size,
                              hipStream_t stream) {
  Params p;
  p.emb_in = (const float*)d_in[0];
  p.stat   = (const float*)d_in[1];
  p.kg     = (const float*)d_in[2];
  p.Wihu = (const float*)d_in[3];   p.bihu = (const float*)d_in[4];
  p.Whhu = (const float*)d_in[5];   p.bhhu = (const float*)d_in[6];
  p.Wihl = (const float*)d_in[7];   p.bihl = (const float*)d_in[8];
  p.Whhl = (const float*)d_in[9];   p.bhhl = (const float*)d_in[10];
  p.wproj = (const float*)d_in[11]; p.bproj = (const float*)d_in[12];
  p.lng  = (const float*)d_in[13];  p.lnb  = (const float*)d_in[14];
  p.Wpred = (const float*)d_in[15]; p.bpred = (const float*)d_in[16];
  p.deltau = (const float*)d_in[17];
  p.deltal = (const float*)d_in[18];
  p.idxu = (const int*)d_in[19];
  p.idxl = (const int*)d_in[20];
  p.idxp = (const int*)d_in[21];
  p.idxk = (const int*)d_in[22];

  p.E    = in_sizes[17];          // 2048
  p.N    = in_sizes[0] / D;       // 150000
  p.NLOC = p.N - NUSER;           // 50000

  p.emb       = (float*)d_out;
  p.loss_slot = (float*)d_out + (size_t)p.N * D;

  char* ws = (char*)d_ws;
  size_t off = 0;
  p.loss_ev = (float*)(ws + off); off += ((size_t)p.E * 4 + 255) & ~(size_t)255;
  p.cnt_u   = (int*)(ws + off);   off += ((size_t)NUSER * 4 + 255) & ~(size_t)255;
  p.cnt_w   = (int*)(ws + off);   off += ((size_t)p.NLOC * 4 + 255) & ~(size_t)255;
  p.cnt_t   = (int*)(ws + off);   off += ((size_t)p.NLOC * 4 + 255) & ~(size_t)255;

  hipLaunchKernelGGL(k_init, dim3(2048), dim3(NT), 0, stream, p);
  hipLaunchKernelGGL(k_main, dim3(GMAIN), dim3(NT), 0, stream, p);
  hipLaunchKernelGGL(k_fin,  dim3(1),    dim3(NT), 0, stream, p);
}

// Round 2
// 250.746 us; speedup vs baseline: 2.5809x; 2.5809x over previous
//
#include <hip/hip_runtime.h>

#define DEVINL static __device__ __forceinline__

constexpr int NUSER = 100000;
constexpr int D     = 128;
constexpr int METAN = 640;
constexpr int NT    = 256;
constexpr int NWORK = 512;    // worker blocks (2/CU, guaranteed co-resident)
constexpr int GRID  = 2048;   // workers + copy blocks
constexpr int KP4   = 160;    // W_pred k/4
constexpr int KR4   = 97;     // RNN combined k: 385 padded to 388 -> 97

struct Params {
  const float *emb_in, *stat, *kg;
  const float *Wihu, *bihu, *Whhu, *bhhu;
  const float *Wihl, *bihl, *Whhl, *bhhl;
  const float *wproj, *bproj, *lng, *lnb, *Wpred, *bpred;
  const float *deltau, *deltal;
  const int *idxu, *idxl, *idxp, *idxk;
  float *emb;        // d_out [N*D]
  float *loss_slot;  // d_out + N*D
  float *WpredT;     // ws [160][256] float4
  float *WrnnT;      // ws [97][256] float4 (cols 0..127 u-cell, 128..255 l-cell)
  float *brnn;       // ws [256]
  float *loss_ev;    // ws [E]
  int *cnt_u, *cnt_w, *cnt_t;   // progress counters
  int *flag_u, *flag_l;         // "row ever written by an event"
  int E, N, NLOC;
};

DEVINL float loadx(const float* p) {
  return __hip_atomic_load(p, __ATOMIC_RELAXED, __HIP_MEMORY_SCOPE_AGENT);
}
DEVINL void storex(float* p, float v) {
  __hip_atomic_store(p, v, __ATOMIC_RELAXED, __HIP_MEMORY_SCOPE_AGENT);
}
DEVINL float dot4(float4 a, float4 b) {
  return a.x*b.x + a.y*b.y + a.z*b.z + a.w*b.w;
}

DEVINL float block_sum(float v, float* s_red) {
  #pragma unroll
  for (int o = 32; o; o >>= 1) v += __shfl_xor(v, o, 64);
  if ((threadIdx.x & 63) == 0) s_red[threadIdx.x >> 6] = v;
  __syncthreads();
  v = s_red[0] + s_red[1] + s_red[2] + s_red[3];
  __syncthreads();
  return v;
}

DEVINL float2 block_sum2(float a, float b, float2* s2) {
  #pragma unroll
  for (int o = 32; o; o >>= 1) { a += __shfl_xor(a, o, 64); b += __shfl_xor(b, o, 64); }
  if ((threadIdx.x & 63) == 0) s2[threadIdx.x >> 6] = make_float2(a, b);
  __syncthreads();
  float2 r;
  r.x = s2[0].x + s2[1].x + s2[2].x + s2[3].x;
  r.y = s2[0].y + s2[1].y + s2[2].y + s2[3].y;
  __syncthreads();
  return r;
}

// transpose weights, fold biases, set written-row flags
__global__ void k_init(Params p) {
  int tid = blockIdx.x * NT + threadIdx.x;
  int stride = gridDim.x * NT;
  for (int e = tid; e < p.E; e += stride) {
    p.flag_u[p.idxu[e]] = 1;
    p.flag_l[p.idxl[e]] = 1;
  }
  // WpredT4[k4][j] = Wpred[j][4k4..4k4+3]  (read-coalesced float4)
  for (int idx = tid; idx < 256 * KP4; idx += stride) {
    int j = idx / KP4, k4 = idx - j * KP4;
    float4 v = *(const float4*)(p.Wpred + (size_t)j * METAN + k4 * 4);
    ((float4*)p.WpredT)[k4 * 256 + j] = v;
  }
  // WrnnT4[k4][j]: col j<128 -> u-cell row j, else l-cell row j-128.
  // k<257: Wih[i][k];  257<=k<385: Whh[i][k-257];  else 0
  for (int idx = tid; idx < 256 * KR4; idx += stride) {
    int j = idx / KR4, k4 = idx - j * KR4;
    int i = j & 127;
    const float* Wih = (j < 128) ? p.Wihu : p.Wihl;
    const float* Whh = (j < 128) ? p.Whhu : p.Whhl;
    float4 v;
    float* vp = (float*)&v;
    #pragma unroll
    for (int e = 0; e < 4; ++e) {
      int k = k4 * 4 + e;
      vp[e] = (k < 257) ? Wih[(size_t)i * 257 + k]
            : (k < 385) ? Whh[(size_t)i * 128 + (k - 257)] : 0.f;
    }
    ((float4*)p.WrnnT)[k4 * 256 + j] = v;
  }
  for (int j = tid; j < 256; j += stride) {
    p.brnn[j] = (j < 128) ? p.bihu[j] + p.bhhu[j]
                          : p.bihl[j - 128] + p.bhhl[j - 128];
  }
}

__global__ __launch_bounds__(NT) void k_main(Params p) {
  __shared__ __align__(16) float s_meta[METAN];
  __shared__ __align__(16) float s_xu[KR4 * 4], s_xl[KR4 * 4];
  __shared__ float s_u[D], s_l[D], s_p[D], s_kg[D], s_sil[D];
  __shared__ float s_red[4];
  __shared__ float2 s_red2[4];
  __shared__ unsigned long long s_redu[4];

  const int tid  = threadIdx.x;
  const int w    = tid >> 6;
  const int lane = tid & 63;

  if (blockIdx.x >= NWORK) {
    // ---- copy blocks: fill rows never written by any event ----
    size_t g0 = (size_t)(blockIdx.x - NWORK) * NT + tid;
    size_t gs = (size_t)(gridDim.x - NWORK) * NT;
    size_t nf4 = (size_t)p.N * (D / 4);
    const float4* src = (const float4*)p.emb_in;
    float4* dst = (float4*)p.emb;
    for (size_t g = g0; g < nf4; g += gs) {
      int row = (int)(g >> 5);
      int fl = (row < NUSER) ? p.flag_u[row] : p.flag_l[row - NUSER];
      if (!fl) dst[g] = src[g];
    }
    return;
  }

  for (int t = blockIdx.x; t < p.E; t += NWORK) {
    const int iu = p.idxu[t];
    const int il = p.idxl[t];
    const int ip = p.idxp[t];
    const int ik = p.idxk[t];
    const int ilr = il + NUSER;
    const int ipr = ip + NUSER;
    const float du = p.deltau[t], dl = p.deltal[t];

    // ---- dependency wait-counts over earlier events (packed 4x16-bit) ----
    unsigned long long pk = 0;
    for (int s = tid; s < t; s += NT) {
      int ius = p.idxu[s], ils = p.idxl[s], ips = p.idxp[s];
      unsigned long long a  = (ius == iu);
      unsigned long long wl = (ils == il);
      unsigned long long b  = (unsigned long long)((ils == il) + (ips == il));
      unsigned long long c  = (ils == ip);
      pk += a | (wl << 16) | (b << 32) | (c << 48);
    }
    #pragma unroll
    for (int o = 32; o; o >>= 1) pk += __shfl_xor(pk, o, 64);
    if (lane == 0) s_redu[w] = pk;
    __syncthreads();
    pk = s_redu[0] + s_redu[1] + s_redu[2] + s_redu[3];
    __syncthreads();
    const int A  = (int)(pk & 0xffff);          // prior writes of user row iu
    const int WL = (int)((pk >> 16) & 0xffff);  // prior writes of loca row il
    const int B  = (int)((pk >> 32) & 0xffff);  // prior touches of loca row il
    const int C  = (int)((pk >> 48) & 0xffff);  // prior writes of loca row ip

    if (tid == 0) {
      int guard = 0;
      while (true) {
        int x = __hip_atomic_load(&p.cnt_u[iu], __ATOMIC_RELAXED, __HIP_MEMORY_SCOPE_AGENT);
        int y = __hip_atomic_load(&p.cnt_t[il], __ATOMIC_RELAXED, __HIP_MEMORY_SCOPE_AGENT);
        int z = __hip_atomic_load(&p.cnt_w[ip], __ATOMIC_RELAXED, __HIP_MEMORY_SCOPE_AGENT);
        if (x >= A && y >= B && z >= C) break;
        if (++guard > (1 << 22)) break;   // safety valve
        __builtin_amdgcn_s_sleep(1);
      }
    }
    __syncthreads();

    // ---- load rows; first touch reads pristine emb_in (enables copy overlap) ----
    {
      int i = tid & 127;
      if (tid < 128) {
        s_u[i]  = A  ? loadx(p.emb + (size_t)iu  * D + i) : p.emb_in[(size_t)iu  * D + i];
        s_p[i]  = C  ? loadx(p.emb + (size_t)ipr * D + i) : p.emb_in[(size_t)ipr * D + i];
        s_kg[i] = p.kg[(size_t)ik * D + i];
        s_meta[384 + i] = p.stat[(size_t)ipr * D + i];
      } else {
        s_l[i]  = WL ? loadx(p.emb + (size_t)ilr * D + i) : p.emb_in[(size_t)ilr * D + i];
        s_sil[i]        = p.stat[(size_t)ilr * D + i];
        s_meta[512 + i] = p.stat[(size_t)iu  * D + i];
      }
    }
    __syncthreads();

    // ---- LayerNorm over [p ; kg], projection, x-vectors ----
    float xln = (tid < 128) ? s_p[tid] : s_kg[tid - 128];
    float mu  = block_sum(xln, s_red) * (1.f / 256.f);
    float dx  = xln - mu;
    float var = block_sum(dx * dx, s_red) * (1.f / 256.f);
    s_meta[128 + tid] = dx * rsqrtf(var + 1e-5f) * p.lng[tid] + p.lnb[tid];
    if (tid < 128) {
      s_meta[tid] = s_u[tid] * (1.f + p.wproj[tid] * du + p.bproj[tid]);
      s_xu[tid] = s_l[tid];           s_xl[tid] = s_u[tid];
      s_xu[257 + tid] = s_u[tid];     s_xl[257 + tid] = s_l[tid];
    } else {
      int i = tid - 128;
      s_xu[128 + i] = s_kg[i];        s_xl[128 + i] = s_kg[i];
    }
    if (tid == 0) {
      s_xu[256] = du; s_xl[256] = dl;
      s_xu[385] = s_xu[386] = s_xu[387] = 0.f;
      s_xl[385] = s_xl[386] = s_xl[387] = 0.f;
    }
    __syncthreads();

    // ---- pred_j = WpredT[:,j] . meta  (thread-per-row, coalesced dwordx4) ----
    const float4* wp = (const float4*)p.WpredT + tid;
    const float4* m4 = (const float4*)s_meta;
    float a0 = 0.f, a1 = 0.f, a2 = 0.f, a3 = 0.f;
    for (int k4 = 0; k4 < KP4; k4 += 4) {
      float4 w0 = wp[(k4 + 0) * 256], w1 = wp[(k4 + 1) * 256];
      float4 w2 = wp[(k4 + 2) * 256], w3 = wp[(k4 + 3) * 256];
      a0 += dot4(w0, m4[k4 + 0]); a1 += dot4(w1, m4[k4 + 1]);
      a2 += dot4(w2, m4[k4 + 2]); a3 += dot4(w3, m4[k4 + 3]);
    }
    float predj = (a0 + a1) + (a2 + a3) + p.bpred[tid];
    float tg = (tid < 128) ? s_l[tid] : s_sil[tid - 128];
    float ep = predj - tg;
    float lossp = block_sum(ep * ep, s_red) * (1.f / 256.f);

    // ---- RNN cells: threads 0..127 u-cell, 128..255 l-cell ----
    const float4* wr = (const float4*)p.WrnnT + tid;
    const float4* x4 = (const float4*)((tid < 128) ? s_xu : s_xl);
    float r0 = 0.f, r1 = 0.f, r2 = 0.f, r3 = 0.f;
    int k4 = 0;
    for (; k4 + 4 <= KR4; k4 += 4) {
      float4 w0 = wr[(k4 + 0) * 256], w1 = wr[(k4 + 1) * 256];
      float4 w2 = wr[(k4 + 2) * 256], w3 = wr[(k4 + 3) * 256];
      r0 += dot4(w0, x4[k4 + 0]); r1 += dot4(w1, x4[k4 + 1]);
      r2 += dot4(w2, x4[k4 + 2]); r3 += dot4(w3, x4[k4 + 3]);
    }
    for (; k4 < KR4; ++k4) r0 += dot4(wr[k4 * 256], x4[k4]);
    float h = tanhf((r0 + r1) + (r2 + r3) + p.brnn[tid]);

    // ---- L2-normalize halves, losses, write back ----
    float h2 = h * h;
    float2 ss = block_sum2((tid < 128) ? h2 : 0.f, (tid < 128) ? 0.f : h2, s_red2);
    float inv = (tid < 128) ? 1.f / fmaxf(sqrtf(ss.x), 1e-12f)
                            : 1.f / fmaxf(sqrtf(ss.y), 1e-12f);
    float newv = h * inv;
    float oldv = (tid < 128) ? s_u[tid] : s_l[tid - 128];
    float e = newv - oldv;
    float e2 = e * e;
    float2 le = block_sum2((tid < 128) ? e2 : 0.f, (tid < 128) ? 0.f : e2, s_red2);
    if (tid == 0) p.loss_ev[t] = lossp + (le.x + le.y) * (1.f / 128.f);

    storex(p.emb + ((tid < 128) ? (size_t)iu * D + tid
                                : (size_t)ilr * D + (tid - 128)), newv);
    __syncthreads();   // drains vmcnt before barrier

    if (tid == 0) {
      __threadfence();                 // data at coherence point before counter bump
      atomicAdd(&p.cnt_u[iu], 1);
      atomicAdd(&p.cnt_t[il], 1);
      atomicAdd(&p.cnt_w[il], 1);
      atomicAdd(&p.cnt_t[ip], 1);
    }
  }
}

__global__ void k_fin(Params p) {
  __shared__ float s_red[4];
  float v = 0.f;
  for (int i = threadIdx.x; i < p.E; i += NT) v += p.loss_ev[i];
  v = block_sum(v, s_red);
  if (threadIdx.x == 0) p.loss_slot[0] = v;
}

extern "C" void kernel_launch(void* const* d_in, const int* in_sizes, int n_in,
                              void* d_out, int out_size, void* d_ws, size_t ws_size,
                              hipStream_t stream) {
  Params p;
  p.emb_in = (const float*)d_in[0];
  p.stat   = (const float*)d_in[1];
  p.kg     = (const float*)d_in[2];
  p.Wihu = (const float*)d_in[3];   p.bihu = (const float*)d_in[4];
  p.Whhu = (const float*)d_in[5];   p.bhhu = (const float*)d_in[6];
  p.Wihl = (const float*)d_in[7];   p.bihl = (const float*)d_in[8];
  p.Whhl = (const float*)d_in[9];   p.bhhl = (const float*)d_in[10];
  p.wproj = (const float*)d_in[11]; p.bproj = (const float*)d_in[12];
  p.lng  = (const float*)d_in[13];  p.lnb  = (const float*)d_in[14];
  p.Wpred = (const float*)d_in[15]; p.bpred = (const float*)d_in[16];
  p.deltau = (const float*)d_in[17];
  p.deltal = (const float*)d_in[18];
  p.idxu = (const int*)d_in[19];
  p.idxl = (const int*)d_in[20];
  p.idxp = (const int*)d_in[21];
  p.idxk = (const int*)d_in[22];

  p.E    = in_sizes[17];
  p.N    = in_sizes[0] / D;
  p.NLOC = p.N - NUSER;

  p.emb       = (float*)d_out;
  p.loss_slot = (float*)d_out + (size_t)p.N * D;

  char* ws = (char*)d_ws;
  size_t off = 0;
  auto take = [&](size_t bytes) {
    void* r = ws + off;
    off += (bytes + 255) & ~(size_t)255;
    return r;
  };
  p.WpredT  = (float*)take((size_t)KP4 * 256 * 16);
  p.WrnnT   = (float*)take((size_t)KR4 * 256 * 16);
  p.brnn    = (float*)take(256 * 4);
  p.loss_ev = (float*)take((size_t)p.E * 4);
  size_t z0 = off;
  p.cnt_u   = (int*)take((size_t)NUSER * 4);
  p.cnt_w   = (int*)take((size_t)p.NLOC * 4);
  p.cnt_t   = (int*)take((size_t)p.NLOC * 4);
  p.flag_u  = (int*)take((size_t)NUSER * 4);
  p.flag_l  = (int*)take((size_t)p.NLOC * 4);
  size_t zbytes = off - z0;

  hipMemsetAsync(ws + z0, 0, zbytes, stream);
  hipLaunchKernelGGL(k_init, dim3(512),  dim3(NT), 0, stream, p);
  hipLaunchKernelGGL(k_main, dim3(GRID), dim3(NT), 0, stream, p);
  hipLaunchKernelGGL(k_fin,  dim3(1),    dim3(NT), 0, stream, p);
}